// Round 8
// baseline (347.439 us; speedup 1.0000x reference)
//
#include <hip/hip_runtime.h>
#include <hip/hip_bf16.h>
#include <stdint.h>

// Problem constants
#define B_ 4
#define T_ 2048
#define D_ 1024
#define H_ 16
#define HD_ 64

typedef __attribute__((ext_vector_type(8))) short bf16x8;
typedef __attribute__((ext_vector_type(4))) float f32x4;
typedef __attribute__((ext_vector_type(16))) float f32x16;

static __device__ __forceinline__ short f2bf(float f) {
    __hip_bfloat16 h = __float2bfloat16(f);
    short s;
    __builtin_memcpy(&s, &h, sizeof(short));
    return s;
}
static __device__ __forceinline__ float bf2f(short s) {
    unsigned u = ((unsigned)(unsigned short)s) << 16;
    float f;
    __builtin_memcpy(&f, &u, sizeof(float));
    return f;
}

static __device__ __forceinline__ void gload16(const void* g, void* l) {
    __builtin_amdgcn_global_load_lds((const __attribute__((address_space(1))) uint32_t*)g,
                                     (__attribute__((address_space(3))) uint32_t*)l,
                                     16, 0, 0);
}

static __device__ __forceinline__ unsigned cvtpk(float lo, float hi) {
    unsigned r;
    asm("v_cvt_pk_bf16_f32 %0, %1, %2" : "=v"(r) : "v"(lo), "v"(hi));
    return r;
}
// v_permlane32_swap_b32: a' = [a_lo32 | b_lo32], b' = [a_hi32 | b_hi32]
static __device__ __forceinline__ void pl32swap(unsigned& a, unsigned& b) {
    asm("v_permlane32_swap_b32 %0, %1" : "+v"(a), "+v"(b));
}

// ---------------- fp32 -> bf16 cast (x) ----------------
__global__ __launch_bounds__(256) void cast_kernel(const float* __restrict__ src,
                                                   short* __restrict__ dst, int n) {
    int i = (blockIdx.x * 256 + threadIdx.x) * 4;
    if (i < n) {
        float4 v = *reinterpret_cast<const float4*>(src + i);
        short4 o;
        o.x = f2bf(v.x); o.y = f2bf(v.y); o.z = f2bf(v.z); o.w = f2bf(v.w);
        *reinterpret_cast<short4*>(dst + i) = o;
    }
}

// ---------------- fused weight cast ----------------
__global__ __launch_bounds__(256) void cast_w_kernel(const float* __restrict__ wq,
                                                     const float* __restrict__ wk,
                                                     const float* __restrict__ wv,
                                                     const float* __restrict__ wo,
                                                     short* __restrict__ wqkv,
                                                     short* __restrict__ wob) {
    int wsel = blockIdx.x >> 10;
    int blk = blockIdx.x & 1023;
    const float* src = wsel == 0 ? wq : (wsel == 1 ? wk : (wsel == 2 ? wv : wo));
    short* dst = wsel == 3 ? wob : (wqkv + (size_t)wsel * 1024 * 1024);
    int i = (blk * 256 + threadIdx.x) * 4;
    float4 v = *reinterpret_cast<const float4*>(src + i);
    short4 o;
    o.x = f2bf(v.x); o.y = f2bf(v.y); o.z = f2bf(v.z); o.w = f2bf(v.w);
    *reinterpret_cast<short4*>(dst + i) = o;
}

// ---------------- GEMM: C[m][n] = sum_k A[m][k]*Bw[n][k] (+bias), BK=64 ----------------
// MODE 0: QKV epilogue (scatter bf16 into (b,h,t,d) layout, per-part bias)
// MODE 1: fp32 out + bias
template <int MODE>
__global__ __launch_bounds__(256) void gemm_kernel(
        const short* __restrict__ A, const short* __restrict__ Bw,
        const float* __restrict__ b0, const float* __restrict__ b1, const float* __restrict__ b2,
        short* __restrict__ q_out, short* __restrict__ k_out, short* __restrict__ v_out,
        float* __restrict__ f_out) {
    const int K = 1024;
    const int n0 = blockIdx.x * 128;
    const int m0 = blockIdx.y * 128;
    const int tid = threadIdx.x;
    const int wid = tid >> 6, lane = tid & 63, g = lane >> 4, c = lane & 15;
    const int wr = wid >> 1, wc = wid & 1;

    __shared__ __align__(16) short As[128 * 64];   // 16 KB
    __shared__ __align__(16) short Bs[128 * 64];   // 16 KB

    f32x4 acc[4][4] = {};

    for (int k0 = 0; k0 < K; k0 += 64) {
        // stage A,B tiles: 16KB each, 256 threads x 16B x 4 rounds
        #pragma unroll
        for (int r = 0; r < 4; ++r) {
            int ci = r * 256 + tid;
            int row = ci >> 3, cc = ci & 7;
            gload16(A + (size_t)(m0 + row) * K + k0 + cc * 8, As + ci * 8);
            gload16(Bw + (size_t)(n0 + row) * K + k0 + cc * 8, Bs + ci * 8);
        }
        __syncthreads();
        #pragma unroll
        for (int ks = 0; ks < 2; ++ks) {   // two K=32 halves, frags scoped to keep VGPR flat
            bf16x8 af[4], bfr[4];
            #pragma unroll
            for (int mt = 0; mt < 4; ++mt)
                af[mt] = *reinterpret_cast<const bf16x8*>(As + (wr * 64 + mt * 16 + c) * 64 + ks * 32 + g * 8);
            #pragma unroll
            for (int nt = 0; nt < 4; ++nt)
                bfr[nt] = *reinterpret_cast<const bf16x8*>(Bs + (wc * 64 + nt * 16 + c) * 64 + ks * 32 + g * 8);
            #pragma unroll
            for (int mt = 0; mt < 4; ++mt) {
                #pragma unroll
                for (int nt = 0; nt < 4; ++nt)
                    acc[mt][nt] = __builtin_amdgcn_mfma_f32_16x16x32_bf16(af[mt], bfr[nt], acc[mt][nt], 0, 0, 0);
            }
        }
        __syncthreads();
    }

    #pragma unroll
    for (int mt = 0; mt < 4; ++mt) {
        #pragma unroll
        for (int nt = 0; nt < 4; ++nt) {
            int n = n0 + wc * 64 + nt * 16 + c;
            if (MODE == 0) {
                int part = n >> 10, n1 = n & 1023;
                const float* bias = part == 0 ? b0 : (part == 1 ? b1 : b2);
                short* op = part == 0 ? q_out : (part == 1 ? k_out : v_out);
                int h = n1 >> 6, d = n1 & 63;
                float bb = bias[n1];
                #pragma unroll
                for (int r = 0; r < 4; ++r) {
                    int m = m0 + wr * 64 + mt * 16 + g * 4 + r;
                    int b = m >> 11, t = m & (T_ - 1);
                    op[((size_t)(b * H_ + h) * T_ + t) * HD_ + d] = f2bf(acc[mt][nt][r] + bb);
                }
            } else {
                float bb = b0[n];
                #pragma unroll
                for (int r = 0; r < 4; ++r) {
                    int m = m0 + wr * 64 + mt * 16 + g * 4 + r;
                    f_out[(size_t)m * 1024 + n] = acc[mt][nt][r] + bb;
                }
            }
        }
    }
}

// ---------------- causal flash attention, 8-wave 32x32 swapped-QK^T, split-K --------
// grid: (12, H, B), 512 threads (8 waves x 32 q = 256 q/block).
// blockIdx.x -> (j2, s, partial) via tables, heavy-first:
//   partial (j2 in 4..7, s in {0,1}): tiles [s*(2*j2+2), (s+1)*(2*j2+2)) -> pO/pml.
//   whole   (j2 in 0..3):             tiles [0, 4*j2+4)                 -> ab.
// Tile work per block in [10,16] (partials) / [4,16] (wholes). 768 blocks total.
__global__ __launch_bounds__(512) void attn_kernel(const short* __restrict__ q,
                                                   const short* __restrict__ k,
                                                   const short* __restrict__ v,
                                                   short* __restrict__ o,
                                                   short* __restrict__ pO,
                                                   float* __restrict__ pml) {
    const int h = blockIdx.y, b = blockIdx.z;
    const size_t base = ((size_t)(b * H_ + h)) * T_ * HD_;
    const int tid = threadIdx.x;
    const int wid = tid >> 6, lane = tid & 63;
    const int ql = lane & 31, hi = lane >> 5;
    const int xr = (ql & 7) << 3;  // XOR swizzle: row&7 == ql&7 for our reads

    // schedule tables (heavy-first): est tiles {16,16,16,14,14,12,12,12,10,10,8,4}
    const int jt[12] = {7, 7, 3, 6, 6, 5, 5, 2, 4, 4, 1, 0};
    const int stt[12] = {0, 1, 0, 0, 1, 0, 1, 0, 0, 1, 0, 0};
    const int ptt[12] = {1, 1, 0, 1, 1, 1, 1, 0, 1, 1, 0, 0};
    const int bxx = blockIdx.x;
    const int j2 = jt[bxx], s = stt[bxx];
    const bool partial = ptt[bxx] != 0;
    int t_begin, t_end;
    if (partial) { t_begin = s * (2 * j2 + 2); t_end = t_begin + 2 * j2 + 2; }
    else         { t_begin = 0;               t_end = 4 * j2 + 4; }

    const int q0b = j2 * 256;
    const int q0w = q0b + wid * 32;
    const int qg = q0w + ql;

    // shorts: [0:8192) K dbuf (2x4096), [8192:16384) Vt dbuf (2x4096).
    // Epilogue reuses all 16384 as O [256 q][64 d] (swizzled).
    __shared__ __align__(16) short lds[16384];

    // K staging: 512 thr x 16B = 8KB tile in ONE gload16/thread.
    const int krr = tid >> 3, ksl = tid & 7;
    // V staging: thread loads V[vkey][8 d @ vd0*8], writes transposed+swizzled (8 u16).
    const int vkey = tid & 63, vd0 = tid >> 6;

    // Q fragments: qf[st] = Q[qg][st*16 + hi*8 .. +7]  (B-operand layout)
    bf16x8 qf[4];
    {
        const short* qrow = q + base + (size_t)qg * HD_ + hi * 8;
        #pragma unroll
        for (int st = 0; st < 4; ++st)
            qf[st] = *reinterpret_cast<const bf16x8*>(qrow + st * 16);
    }

    f32x16 oT0 = {}, oT1 = {};      // O^T: col q = lane&31, rows d (+0/+32)
    float m_r = -1e30f, l_r = 0.f;  // log2-domain running stats

    // prologue: stage tile t_begin into buf 0
    {
        const int kv0 = t_begin * 64;
        gload16(k + base + (size_t)(kv0 + krr) * HD_ + ((ksl ^ (krr & 7)) << 3), lds + tid * 8);
        bf16x8 vv = *reinterpret_cast<const bf16x8*>(v + base + (size_t)(kv0 + vkey) * HD_ + vd0 * 8);
        #pragma unroll
        for (int jx = 0; jx < 8; ++jx)
            lds[8192 + (vd0 * 8 + jx) * 64 + (vkey ^ (jx << 3))] = vv[jx];
    }
    __syncthreads();

    int buf = 0;
    for (int t0 = t_begin; t0 < t_end; ++t0) {
        const int kv0 = t0 * 64;
        const bool pf = (t0 + 1 < t_end);
        bf16x8 vnext;
        if (pf) {
            gload16(k + base + (size_t)(kv0 + 64 + krr) * HD_ + ((ksl ^ (krr & 7)) << 3),
                    lds + (buf ^ 1) * 4096 + tid * 8);
            vnext = *reinterpret_cast<const bf16x8*>(v + base + (size_t)(kv0 + 64 + vkey) * HD_ + vd0 * 8);
        }

        if (kv0 <= q0w + 31) {  // wave has unmasked keys in this tile
            const short* Kb = lds + buf * 4096;
            const short* Vb = lds + 8192 + buf * 4096;

            f32x16 s0 = {}, s1 = {};
            __builtin_amdgcn_s_setprio(1);
            #pragma unroll
            for (int st = 0; st < 4; ++st) {
                int coff = (st * 16 + hi * 8) ^ xr;
                bf16x8 ka0 = *reinterpret_cast<const bf16x8*>(Kb + ql * 64 + coff);
                bf16x8 ka1 = *reinterpret_cast<const bf16x8*>(Kb + (32 + ql) * 64 + coff);
                s0 = __builtin_amdgcn_mfma_f32_32x32x16_bf16(ka0, qf[st], s0, 0, 0, 0);
                s1 = __builtin_amdgcn_mfma_f32_32x32x16_bf16(ka1, qf[st], s1, 0, 0, 0);
            }
            __builtin_amdgcn_s_setprio(0);

            const float SC = 0.18033688f;  // (1/sqrt(64)) * log2(e)
            if (kv0 + 63 <= q0w) {
                #pragma unroll
                for (int i = 0; i < 16; ++i) { s0[i] *= SC; s1[i] *= SC; }
            } else {  // diagonal tile: causal mask
                #pragma unroll
                for (int i = 0; i < 16; ++i) {
                    int krow = (i & 3) + 8 * (i >> 2) + 4 * hi;
                    s0[i] = (kv0 + krow > qg) ? -1e30f : s0[i] * SC;
                    s1[i] = (kv0 + 32 + krow > qg) ? -1e30f : s1[i] * SC;
                }
            }

            // tile max: depth-5 tree + cross-half
            float t8[8], t4[4], t2[2], tm;
            {
                f32x16 mx;
                #pragma unroll
                for (int i = 0; i < 16; ++i) mx[i] = fmaxf(s0[i], s1[i]);
                #pragma unroll
                for (int i = 0; i < 8; ++i) t8[i] = fmaxf(mx[i], mx[i + 8]);
                #pragma unroll
                for (int i = 0; i < 4; ++i) t4[i] = fmaxf(t8[i], t8[i + 4]);
                t2[0] = fmaxf(t4[0], t4[2]); t2[1] = fmaxf(t4[1], t4[3]);
                tm = fmaxf(t2[0], t2[1]);
            }
            tm = fmaxf(tm, __shfl_xor(tm, 32, 64));

            // defer-max (T13)
            if (!__all(tm <= m_r + 8.f)) {
                float mn = fmaxf(m_r, tm);
                float al = exp2f(m_r - mn);
                m_r = mn;
                l_r *= al;
                #pragma unroll
                for (int i = 0; i < 16; ++i) { oT0[i] *= al; oT1[i] *= al; }
            }

            #pragma unroll
            for (int i = 0; i < 16; ++i) s0[i] = exp2f(s0[i] - m_r);
            #pragma unroll
            for (int i = 0; i < 16; ++i) s1[i] = exp2f(s1[i] - m_r);

            // tile sum: depth-5 tree
            {
                f32x16 sv = s0 + s1;
                #pragma unroll
                for (int i = 0; i < 8; ++i) t8[i] = sv[i] + sv[i + 8];
                #pragma unroll
                for (int i = 0; i < 4; ++i) t4[i] = t8[i] + t8[i + 4];
                t2[0] = t4[0] + t4[2]; t2[1] = t4[1] + t4[3];
                float ts = t2[0] + t2[1];
                ts += __shfl_xor(ts, 32, 64);
                l_r += ts;
            }

            // P^T -> bf16 B-fragments
            unsigned c[16];
            #pragma unroll
            for (int i = 0; i < 8; ++i) c[i] = cvtpk(s0[2 * i], s0[2 * i + 1]);
            #pragma unroll
            for (int i = 0; i < 8; ++i) c[8 + i] = cvtpk(s1[2 * i], s1[2 * i + 1]);
            pl32swap(c[0], c[2]);   pl32swap(c[1], c[3]);
            pl32swap(c[4], c[6]);   pl32swap(c[5], c[7]);
            pl32swap(c[8], c[10]);  pl32swap(c[9], c[11]);
            pl32swap(c[12], c[14]); pl32swap(c[13], c[15]);
            union { unsigned u[4]; bf16x8 v8; } pb[4];
            #pragma unroll
            for (int ksx = 0; ksx < 4; ++ksx) {
                #pragma unroll
                for (int jx = 0; jx < 4; ++jx) pb[ksx].u[jx] = c[ksx * 4 + jx];
            }

            // PV: O^T += V^T * P^T
            __builtin_amdgcn_s_setprio(1);
            #pragma unroll
            for (int ksx = 0; ksx < 4; ++ksx) {
                int coff = (ksx * 16 + hi * 8) ^ xr;
                bf16x8 va0 = *reinterpret_cast<const bf16x8*>(Vb + ql * 64 + coff);
                bf16x8 va1 = *reinterpret_cast<const bf16x8*>(Vb + (32 + ql) * 64 + coff);
                oT0 = __builtin_amdgcn_mfma_f32_32x32x16_bf16(va0, pb[ksx].v8, oT0, 0, 0, 0);
                oT1 = __builtin_amdgcn_mfma_f32_32x32x16_bf16(va1, pb[ksx].v8, oT1, 0, 0, 0);
            }
            __builtin_amdgcn_s_setprio(0);
        }

        if (pf) {
            #pragma unroll
            for (int jx = 0; jx < 8; ++jx)
                lds[8192 + (buf ^ 1) * 4096 + (vd0 * 8 + jx) * 64 + (vkey ^ (jx << 3))] = vnext[jx];
        }
        __syncthreads();
        buf ^= 1;
    }

    // epilogue: normalize, transpose via LDS (full 32KB as [256 q][64 d], swizzled)
    float inv = 1.f / l_r;
    const int row = wid * 32 + ql;  // 0..255; row&7 == ql&7 == xr>>3
    #pragma unroll
    for (int i = 0; i < 16; ++i) {
        int d0 = (i & 3) + 8 * (i >> 2) + 4 * hi;
        lds[row * 64 + (d0 ^ xr)] = f2bf(oT0[i] * inv);
        lds[row * 64 + ((d0 + 32) ^ xr)] = f2bf(oT1[i] * inv);
    }
    if (partial && hi == 0) {
        size_t prow = ((((size_t)(b * H_ + h)) * 4 + (j2 - 4)) * 2 + s) * 256 + row;
        *reinterpret_cast<float2*>(pml + prow * 2) = make_float2(m_r, l_r);
    }
    __syncthreads();
    if (partial) {
        size_t prow0 = ((((size_t)(b * H_ + h)) * 4 + (j2 - 4)) * 2 + s) * 256;
        #pragma unroll
        for (int rr = 0; rr < 4; ++rr) {
            int orow = rr * 64 + (tid >> 3);
            int sl = tid & 7;
            bf16x8 val = *reinterpret_cast<const bf16x8*>(lds + orow * 64 + ((sl ^ (orow & 7)) << 3));
            *reinterpret_cast<bf16x8*>(pO + (prow0 + orow) * 64 + sl * 8) = val;
        }
    } else {
        #pragma unroll
        for (int rr = 0; rr < 4; ++rr) {
            int orow = rr * 64 + (tid >> 3);
            int sl = tid & 7;
            bf16x8 val = *reinterpret_cast<const bf16x8*>(lds + orow * 64 + ((sl ^ (orow & 7)) << 3));
            *reinterpret_cast<bf16x8*>(o + ((size_t)(b * T_ + q0b + orow)) * D_ + h * HD_ + sl * 8) = val;
        }
    }
}

// ---------------- split-K merge: combine the two KV-halves for q-blocks j2>=4 -------
// one thread per (row, 8-d chunk): 64bh x 4 j2 x 256 rows x 8 chunks = 524288 threads
__global__ __launch_bounds__(256) void merge_kernel(const short* __restrict__ pO,
                                                    const float* __restrict__ pml,
                                                    short* __restrict__ ab) {
    int gid = blockIdx.x * 256 + threadIdx.x;
    int d8 = gid & 7;
    int r  = (gid >> 3) & 255;
    int jj = (gid >> 11) & 3;
    int bh = gid >> 13;
    int b = bh >> 4, h = bh & 15;
    size_t prow0 = (((size_t)bh * 4 + jj) * 2) * 256;  // s=0 row base; s=1 = +256
    float m0 = pml[(prow0 + r) * 2],       l0 = pml[(prow0 + r) * 2 + 1];
    float m1 = pml[(prow0 + 256 + r) * 2], l1 = pml[(prow0 + 256 + r) * 2 + 1];
    float M = fmaxf(m0, m1);
    float w0 = exp2f(m0 - M) * l0, w1 = exp2f(m1 - M) * l1;
    float inv = 1.f / (w0 + w1);
    w0 *= inv; w1 *= inv;
    bf16x8 a = *reinterpret_cast<const bf16x8*>(pO + (prow0 + r) * 64 + d8 * 8);
    bf16x8 c = *reinterpret_cast<const bf16x8*>(pO + (prow0 + 256 + r) * 64 + d8 * 8);
    short res[8];
    #pragma unroll
    for (int i = 0; i < 8; ++i) res[i] = f2bf(w0 * bf2f(a[i]) + w1 * bf2f(c[i]));
    int t = (jj + 4) * 256 + r;
    *reinterpret_cast<bf16x8*>(ab + ((size_t)(b * T_ + t)) * D_ + h * HD_ + d8 * 8) =
        *reinterpret_cast<const bf16x8*>(res);
}

extern "C" void kernel_launch(void* const* d_in, const int* in_sizes, int n_in,
                              void* d_out, int out_size, void* d_ws, size_t ws_size,
                              hipStream_t stream) {
    const float* x  = (const float*)d_in[0];
    // d_in[1] = causal mask — structure known (triu k=1), ignored
    const float* Wq = (const float*)d_in[2];
    const float* bq = (const float*)d_in[3];
    const float* Wk = (const float*)d_in[4];
    const float* bk = (const float*)d_in[5];
    const float* Wv = (const float*)d_in[6];
    const float* bv = (const float*)d_in[7];
    const float* Wo = (const float*)d_in[8];
    const float* bo = (const float*)d_in[9];
    float* out = (float*)d_out;

    const size_t NX = (size_t)B_ * T_ * D_;   // 8388608
    const size_t NW = (size_t)D_ * D_;        // 1048576

    // ws layout (shorts). ab aliases xb: x dead after GEMM1; stream serializes.
    short* ws   = (short*)d_ws;
    short* xb   = ws;                //  x  bf16             (16 MB)
    short* ab   = ws;                //  attn out, aliases xb
    short* wqkv = xb + NX;           //  [Wq;Wk;Wv] bf16     ( 6 MB)
    short* wob  = wqkv + 3 * NW;     //  Wo bf16             ( 2 MB)
    short* qb   = wob + NW;          //  q (b,h,t,d) bf16    (16 MB)
    short* kb   = qb + NX;           //                      (16 MB)
    short* vb   = kb + NX;           //                      (16 MB)
    // split-K partials live in d_out (33.5 MB) used as scratch: pO 16.78 MB +
    // pml 1.05 MB; gemm2 fully overwrites d_out afterwards.
    short* pO   = (short*)d_out;
    float* pml  = (float*)((short*)d_out + (size_t)64 * 4 * 2 * 256 * 64);

    cast_kernel<<<(int)(NX / 1024), 256, 0, stream>>>(x, xb, (int)NX);
    cast_w_kernel<<<4096, 256, 0, stream>>>(Wq, Wk, Wv, Wo, wqkv, wob);

    gemm_kernel<0><<<dim3(24, 64), 256, 0, stream>>>(xb, wqkv, bq, bk, bv, qb, kb, vb, nullptr);
    attn_kernel<<<dim3(12, H_, B_), 512, 0, stream>>>(qb, kb, vb, ab, pO, pml);
    merge_kernel<<<2048, 256, 0, stream>>>(pO, pml, ab);
    gemm_kernel<1><<<dim3(8, 64), 256, 0, stream>>>(ab, wob, bo, nullptr, nullptr, nullptr,
                                                    nullptr, nullptr, out);
}

// Round 9
// 322.300 us; speedup vs baseline: 1.0780x; 1.0780x over previous
//
#include <hip/hip_runtime.h>
#include <hip/hip_bf16.h>
#include <stdint.h>

// Problem constants
#define B_ 4
#define T_ 2048
#define D_ 1024
#define H_ 16
#define HD_ 64

typedef __attribute__((ext_vector_type(8))) short bf16x8;
typedef __attribute__((ext_vector_type(4))) float f32x4;
typedef __attribute__((ext_vector_type(16))) float f32x16;

static __device__ __forceinline__ short f2bf(float f) {
    __hip_bfloat16 h = __float2bfloat16(f);
    short s;
    __builtin_memcpy(&s, &h, sizeof(short));
    return s;
}
static __device__ __forceinline__ float bf2f(short s) {
    unsigned u = ((unsigned)(unsigned short)s) << 16;
    float f;
    __builtin_memcpy(&f, &u, sizeof(float));
    return f;
}

static __device__ __forceinline__ void gload16(const void* g, void* l) {
    __builtin_amdgcn_global_load_lds((const __attribute__((address_space(1))) uint32_t*)g,
                                     (__attribute__((address_space(3))) uint32_t*)l,
                                     16, 0, 0);
}

static __device__ __forceinline__ unsigned cvtpk(float lo, float hi) {
    unsigned r;
    asm("v_cvt_pk_bf16_f32 %0, %1, %2" : "=v"(r) : "v"(lo), "v"(hi));
    return r;
}
// v_permlane32_swap_b32: a' = [a_lo32 | b_lo32], b' = [a_hi32 | b_hi32]
static __device__ __forceinline__ void pl32swap(unsigned& a, unsigned& b) {
    asm("v_permlane32_swap_b32 %0, %1" : "+v"(a), "+v"(b));
}

// ---------------- fp32 -> bf16 cast (x) ----------------
__global__ __launch_bounds__(256) void cast_kernel(const float* __restrict__ src,
                                                   short* __restrict__ dst, int n) {
    int i = (blockIdx.x * 256 + threadIdx.x) * 4;
    if (i < n) {
        float4 v = *reinterpret_cast<const float4*>(src + i);
        short4 o;
        o.x = f2bf(v.x); o.y = f2bf(v.y); o.z = f2bf(v.z); o.w = f2bf(v.w);
        *reinterpret_cast<short4*>(dst + i) = o;
    }
}

// ---------------- fused weight cast ----------------
__global__ __launch_bounds__(256) void cast_w_kernel(const float* __restrict__ wq,
                                                     const float* __restrict__ wk,
                                                     const float* __restrict__ wv,
                                                     const float* __restrict__ wo,
                                                     short* __restrict__ wqkv,
                                                     short* __restrict__ wob) {
    int wsel = blockIdx.x >> 10;
    int blk = blockIdx.x & 1023;
    const float* src = wsel == 0 ? wq : (wsel == 1 ? wk : (wsel == 2 ? wv : wo));
    short* dst = wsel == 3 ? wob : (wqkv + (size_t)wsel * 1024 * 1024);
    int i = (blk * 256 + threadIdx.x) * 4;
    float4 v = *reinterpret_cast<const float4*>(src + i);
    short4 o;
    o.x = f2bf(v.x); o.y = f2bf(v.y); o.z = f2bf(v.z); o.w = f2bf(v.w);
    *reinterpret_cast<short4*>(dst + i) = o;
}

// ---------------- GEMM (m97 structure, BK=32 — round-7 proven version) ----------------
template <int MODE>
__global__ __launch_bounds__(256) void gemm_kernel(
        const short* __restrict__ A, const short* __restrict__ Bw,
        const float* __restrict__ b0, const float* __restrict__ b1, const float* __restrict__ b2,
        short* __restrict__ q_out, short* __restrict__ k_out, short* __restrict__ v_out,
        float* __restrict__ f_out) {
    const int K = 1024;
    const int n0 = blockIdx.x * 128;
    const int m0 = blockIdx.y * 128;
    const int tid = threadIdx.x;
    const int wid = tid >> 6, lane = tid & 63, g = lane >> 4, c = lane & 15;
    const int wr = wid >> 1, wc = wid & 1;

    __shared__ __align__(16) short As[128 * 32];
    __shared__ __align__(16) short Bs[128 * 32];

    f32x4 acc[4][4] = {};

    for (int k0 = 0; k0 < K; k0 += 32) {
        #pragma unroll
        for (int r = 0; r < 2; ++r) {
            int ci = r * 256 + tid;
            int row = ci >> 2, cc = ci & 3;
            gload16(A + (size_t)(m0 + row) * K + k0 + cc * 8, As + ci * 8);
            gload16(Bw + (size_t)(n0 + row) * K + k0 + cc * 8, Bs + ci * 8);
        }
        __syncthreads();
        bf16x8 af[4], bfr[4];
        #pragma unroll
        for (int mt = 0; mt < 4; ++mt)
            af[mt] = *reinterpret_cast<const bf16x8*>(As + (wr * 64 + mt * 16 + c) * 32 + g * 8);
        #pragma unroll
        for (int nt = 0; nt < 4; ++nt)
            bfr[nt] = *reinterpret_cast<const bf16x8*>(Bs + (wc * 64 + nt * 16 + c) * 32 + g * 8);
        #pragma unroll
        for (int mt = 0; mt < 4; ++mt) {
            #pragma unroll
            for (int nt = 0; nt < 4; ++nt)
                acc[mt][nt] = __builtin_amdgcn_mfma_f32_16x16x32_bf16(af[mt], bfr[nt], acc[mt][nt], 0, 0, 0);
        }
        __syncthreads();
    }

    #pragma unroll
    for (int mt = 0; mt < 4; ++mt) {
        #pragma unroll
        for (int nt = 0; nt < 4; ++nt) {
            int n = n0 + wc * 64 + nt * 16 + c;
            if (MODE == 0) {
                int part = n >> 10, n1 = n & 1023;
                const float* bias = part == 0 ? b0 : (part == 1 ? b1 : b2);
                short* op = part == 0 ? q_out : (part == 1 ? k_out : v_out);
                int h = n1 >> 6, d = n1 & 63;
                float bb = bias[n1];
                #pragma unroll
                for (int r = 0; r < 4; ++r) {
                    int m = m0 + wr * 64 + mt * 16 + g * 4 + r;
                    int b = m >> 11, t = m & (T_ - 1);
                    op[((size_t)(b * H_ + h) * T_ + t) * HD_ + d] = f2bf(acc[mt][nt][r] + bb);
                }
            } else {
                float bb = b0[n];
                #pragma unroll
                for (int r = 0; r < 4; ++r) {
                    int m = m0 + wr * 64 + mt * 16 + g * 4 + r;
                    f_out[(size_t)m * 1024 + n] = acc[mt][nt][r] + bb;
                }
            }
        }
    }
}

// ---------------- causal flash attention, 4-wave 32x32 swapped-QK^T, split-K --------
// Round-7 geometry (grid (24,H,B), 256 thr, balanced split-K) + T4 counted-vmcnt
// pipeline: K double-prefetch through 3 rotating LDS buffers crossing RAW s_barrier
// with s_waitcnt vmcnt(2) (never drains in steady state); V reg-staged 1 ahead,
// issued BEFORE K-gloads so the V-write's implicit wait leaves K(t+2) in flight.
__global__ __launch_bounds__(256) void attn_kernel(const short* __restrict__ q,
                                                   const short* __restrict__ k,
                                                   const short* __restrict__ v,
                                                   short* __restrict__ o,
                                                   short* __restrict__ pO,
                                                   float* __restrict__ pml) {
    const int h = blockIdx.y, b = blockIdx.z;
    const size_t base = ((size_t)(b * H_ + h)) * T_ * HD_;
    const int tid = threadIdx.x;
    const int wid = tid >> 6, lane = tid & 63;
    const int ql = lane & 31, hi = lane >> 5;
    const int xr = (ql & 7) << 3;  // XOR swizzle: row&7 == ql&7 for our reads

    const int bxx = blockIdx.x;
    const int grp = bxx / 3, r3 = bxx - grp * 3;
    int j, t_begin, t_end, s = 0;
    bool partial;
    if (r3 < 2) { partial = true;  j = 15 - grp; s = r3; t_begin = s * (j + 1); t_end = t_begin + (j + 1); }
    else        { partial = false; j = 7 - grp;  t_begin = 0; t_end = 2 * j + 2; }

    const int q0b = j * 128;
    const int q0w = q0b + wid * 32;
    const int qg = q0w + ql;

    // shorts: K bufs [0,12288) = 3 x 4096; V bufs [12288,20480) = 2 x 4096.
    // Epilogue reuses [12288,20480) as O [128 q][64 d] (swizzled). 40 KB total.
    __shared__ __align__(16) short lds[20480];

    const int krr = tid >> 3, ksl = tid & 7;
    const int vkey = tid & 63, vd0b = tid >> 6;

    // Q fragments: qf[st] = Q[qg][st*16 + hi*8 .. +7]  (B-operand layout)
    bf16x8 qf[4];
    {
        const short* qrow = q + base + (size_t)qg * HD_ + hi * 8;
        #pragma unroll
        for (int st = 0; st < 4; ++st)
            qf[st] = *reinterpret_cast<const bf16x8*>(qrow + st * 16);
    }

    f32x16 oT0 = {}, oT1 = {};      // O^T: col q = lane&31, rows d (+0/+32)
    float m_r = -1e30f, l_r = 0.f;  // log2-domain running stats

    int kcur = 0, knx = 1, knx2 = 2, vcur = 0;

    // ---- prologue: V(t0) load; K(t0), K(t0+1) gloads; V(t0) write; counted wait ----
    {
        const int kv0 = t_begin * 64;
        bf16x8 vv[2];
        #pragma unroll
        for (int cc = 0; cc < 2; ++cc)
            vv[cc] = *reinterpret_cast<const bf16x8*>(v + base + (size_t)(kv0 + vkey) * HD_ + (vd0b + cc * 4) * 8);
        __builtin_amdgcn_sched_barrier(0);
        #pragma unroll
        for (int r = 0; r < 2; ++r) {
            int row = r * 32 + krr;
            gload16(k + base + (size_t)(kv0 + row) * HD_ + ((ksl ^ (row & 7)) << 3),
                    lds + r * 2048 + tid * 8);
        }
        if (t_begin + 1 < t_end) {
            #pragma unroll
            for (int r = 0; r < 2; ++r) {
                int row = r * 32 + krr;
                gload16(k + base + (size_t)(kv0 + 64 + row) * HD_ + ((ksl ^ (row & 7)) << 3),
                        lds + 4096 + r * 2048 + tid * 8);
            }
        }
        __builtin_amdgcn_sched_barrier(0);
        #pragma unroll
        for (int cc = 0; cc < 2; ++cc) {
            int vd0 = vd0b + cc * 4;
            #pragma unroll
            for (int jx = 0; jx < 8; ++jx)
                lds[12288 + (vd0 * 8 + jx) * 64 + (vkey ^ (jx << 3))] = vv[cc][jx];
        }
        if (t_begin + 1 < t_end)
            asm volatile("s_waitcnt vmcnt(2) lgkmcnt(0)" ::: "memory");
        else
            asm volatile("s_waitcnt vmcnt(0) lgkmcnt(0)" ::: "memory");
        __builtin_amdgcn_s_barrier();
        __builtin_amdgcn_sched_barrier(0);
    }

    for (int t0 = t_begin; t0 < t_end; ++t0) {
        const int kv0 = t0 * 64;
        const bool pf1 = (t0 + 1 < t_end);
        const bool pf2 = (t0 + 2 < t_end);

        bf16x8 vn[2];
        if (pf1) {
            #pragma unroll
            for (int cc = 0; cc < 2; ++cc)
                vn[cc] = *reinterpret_cast<const bf16x8*>(
                    v + base + (size_t)(kv0 + 64 + vkey) * HD_ + (vd0b + cc * 4) * 8);
        }
        __builtin_amdgcn_sched_barrier(0);
        if (pf2) {
            #pragma unroll
            for (int r = 0; r < 2; ++r) {
                int row = r * 32 + krr;
                gload16(k + base + (size_t)(kv0 + 128 + row) * HD_ + ((ksl ^ (row & 7)) << 3),
                        lds + knx2 * 4096 + r * 2048 + tid * 8);
            }
        }
        __builtin_amdgcn_sched_barrier(0);

        if (kv0 <= q0w + 31) {  // wave has unmasked keys in this tile
            const short* Kb = lds + kcur * 4096;
            const short* Vb = lds + 12288 + vcur * 4096;

            f32x16 s0 = {}, s1 = {};
            __builtin_amdgcn_s_setprio(1);
            #pragma unroll
            for (int st = 0; st < 4; ++st) {
                int coff = (st * 16 + hi * 8) ^ xr;
                bf16x8 ka0 = *reinterpret_cast<const bf16x8*>(Kb + ql * 64 + coff);
                bf16x8 ka1 = *reinterpret_cast<const bf16x8*>(Kb + (32 + ql) * 64 + coff);
                s0 = __builtin_amdgcn_mfma_f32_32x32x16_bf16(ka0, qf[st], s0, 0, 0, 0);
                s1 = __builtin_amdgcn_mfma_f32_32x32x16_bf16(ka1, qf[st], s1, 0, 0, 0);
            }
            __builtin_amdgcn_s_setprio(0);

            const float SC = 0.18033688f;  // (1/sqrt(64)) * log2(e)
            if (kv0 + 63 <= q0w) {
                #pragma unroll
                for (int i = 0; i < 16; ++i) { s0[i] *= SC; s1[i] *= SC; }
            } else {  // diagonal tile: causal mask
                #pragma unroll
                for (int i = 0; i < 16; ++i) {
                    int krow = (i & 3) + 8 * (i >> 2) + 4 * hi;
                    s0[i] = (kv0 + krow > qg) ? -1e30f : s0[i] * SC;
                    s1[i] = (kv0 + 32 + krow > qg) ? -1e30f : s1[i] * SC;
                }
            }

            // tile max: depth-5 tree + cross-half
            float t8[8], t4[4], t2[2], tm;
            {
                f32x16 mx;
                #pragma unroll
                for (int i = 0; i < 16; ++i) mx[i] = fmaxf(s0[i], s1[i]);
                #pragma unroll
                for (int i = 0; i < 8; ++i) t8[i] = fmaxf(mx[i], mx[i + 8]);
                #pragma unroll
                for (int i = 0; i < 4; ++i) t4[i] = fmaxf(t8[i], t8[i + 4]);
                t2[0] = fmaxf(t4[0], t4[2]); t2[1] = fmaxf(t4[1], t4[3]);
                tm = fmaxf(t2[0], t2[1]);
            }
            tm = fmaxf(tm, __shfl_xor(tm, 32, 64));

            // defer-max (T13)
            if (!__all(tm <= m_r + 8.f)) {
                float mn = fmaxf(m_r, tm);
                float al = exp2f(m_r - mn);
                m_r = mn;
                l_r *= al;
                #pragma unroll
                for (int i = 0; i < 16; ++i) { oT0[i] *= al; oT1[i] *= al; }
            }

            #pragma unroll
            for (int i = 0; i < 16; ++i) s0[i] = exp2f(s0[i] - m_r);
            #pragma unroll
            for (int i = 0; i < 16; ++i) s1[i] = exp2f(s1[i] - m_r);

            // tile sum: depth-5 tree
            {
                f32x16 sv = s0 + s1;
                #pragma unroll
                for (int i = 0; i < 8; ++i) t8[i] = sv[i] + sv[i + 8];
                #pragma unroll
                for (int i = 0; i < 4; ++i) t4[i] = t8[i] + t8[i + 4];
                t2[0] = t4[0] + t4[2]; t2[1] = t4[1] + t4[3];
                float ts = t2[0] + t2[1];
                ts += __shfl_xor(ts, 32, 64);
                l_r += ts;
            }

            // P^T -> bf16 B-fragments
            unsigned c[16];
            #pragma unroll
            for (int i = 0; i < 8; ++i) c[i] = cvtpk(s0[2 * i], s0[2 * i + 1]);
            #pragma unroll
            for (int i = 0; i < 8; ++i) c[8 + i] = cvtpk(s1[2 * i], s1[2 * i + 1]);
            pl32swap(c[0], c[2]);   pl32swap(c[1], c[3]);
            pl32swap(c[4], c[6]);   pl32swap(c[5], c[7]);
            pl32swap(c[8], c[10]);  pl32swap(c[9], c[11]);
            pl32swap(c[12], c[14]); pl32swap(c[13], c[15]);
            union { unsigned u[4]; bf16x8 v8; } pb[4];
            #pragma unroll
            for (int ksx = 0; ksx < 4; ++ksx) {
                #pragma unroll
                for (int jx = 0; jx < 4; ++jx) pb[ksx].u[jx] = c[ksx * 4 + jx];
            }

            // PV: O^T += V^T * P^T
            __builtin_amdgcn_s_setprio(1);
            #pragma unroll
            for (int ksx = 0; ksx < 4; ++ksx) {
                int coff = (ksx * 16 + hi * 8) ^ xr;
                bf16x8 va0 = *reinterpret_cast<const bf16x8*>(Vb + ql * 64 + coff);
                bf16x8 va1 = *reinterpret_cast<const bf16x8*>(Vb + (32 + ql) * 64 + coff);
                oT0 = __builtin_amdgcn_mfma_f32_32x32x16_bf16(va0, pb[ksx].v8, oT0, 0, 0, 0);
                oT1 = __builtin_amdgcn_mfma_f32_32x32x16_bf16(va1, pb[ksx].v8, oT1, 0, 0, 0);
            }
            __builtin_amdgcn_s_setprio(0);
        }

        if (pf1) {
            // V(t+1) -> alternate V buffer (implicit wait leaves K(t+2) in flight)
            #pragma unroll
            for (int cc = 0; cc < 2; ++cc) {
                int vd0 = vd0b + cc * 4;
                #pragma unroll
                for (int jx = 0; jx < 8; ++jx)
                    lds[12288 + (vcur ^ 1) * 4096 + (vd0 * 8 + jx) * 64 + (vkey ^ (jx << 3))] = vn[cc][jx];
            }
            if (pf2)
                asm volatile("s_waitcnt vmcnt(2) lgkmcnt(0)" ::: "memory");
            else
                asm volatile("s_waitcnt vmcnt(0) lgkmcnt(0)" ::: "memory");
            __builtin_amdgcn_s_barrier();
            __builtin_amdgcn_sched_barrier(0);
        }

        int tmpk = kcur; kcur = knx; knx = knx2; knx2 = tmpk;
        vcur ^= 1;
    }
    __syncthreads();  // all waves done before reusing V region for epilogue

    // epilogue: normalize, transpose via LDS (V region, swizzled), coalesced stores
    float inv = 1.f / l_r;
    const int row = wid * 32 + ql;  // 0..127; row&7 == ql&7 == xr>>3
    #pragma unroll
    for (int i = 0; i < 16; ++i) {
        int d0 = (i & 3) + 8 * (i >> 2) + 4 * hi;
        lds[12288 + row * 64 + (d0 ^ xr)] = f2bf(oT0[i] * inv);
        lds[12288 + row * 64 + ((d0 + 32) ^ xr)] = f2bf(oT1[i] * inv);
    }
    if (partial && hi == 0) {
        size_t prow = ((((size_t)(b * H_ + h)) * 8 + (j - 8)) * 2 + s) * 128 + row;
        *reinterpret_cast<float2*>(pml + prow * 2) = make_float2(m_r, l_r);
    }
    __syncthreads();
    if (partial) {
        size_t prow0 = ((((size_t)(b * H_ + h)) * 8 + (j - 8)) * 2 + s) * 128;
        #pragma unroll
        for (int rr = 0; rr < 4; ++rr) {
            int orow = rr * 32 + (tid >> 3);
            int sl = tid & 7;
            bf16x8 val = *reinterpret_cast<const bf16x8*>(lds + 12288 + orow * 64 + ((sl ^ (orow & 7)) << 3));
            *reinterpret_cast<bf16x8*>(pO + (prow0 + orow) * 64 + sl * 8) = val;
        }
    } else {
        #pragma unroll
        for (int rr = 0; rr < 4; ++rr) {
            int orow = rr * 32 + (tid >> 3);
            int sl = tid & 7;
            bf16x8 val = *reinterpret_cast<const bf16x8*>(lds + 12288 + orow * 64 + ((sl ^ (orow & 7)) << 3));
            *reinterpret_cast<bf16x8*>(o + ((size_t)(b * T_ + q0b + orow)) * D_ + h * HD_ + sl * 8) = val;
        }
    }
}

// ---------------- split-K merge: combine the two KV-halves for q-blocks j>=8 -------
__global__ __launch_bounds__(256) void merge_kernel(const short* __restrict__ pO,
                                                    const float* __restrict__ pml,
                                                    short* __restrict__ ab) {
    int gid = blockIdx.x * 256 + threadIdx.x;
    int d8 = gid & 7;
    int r  = (gid >> 3) & 127;
    int jj = (gid >> 10) & 7;
    int bh = gid >> 13;
    int b = bh >> 4, h = bh & 15;
    size_t prow0 = (((size_t)bh * 8 + jj) * 2) * 128;  // s=0 row base; s=1 = +128
    float m0 = pml[(prow0 + r) * 2],       l0 = pml[(prow0 + r) * 2 + 1];
    float m1 = pml[(prow0 + 128 + r) * 2], l1 = pml[(prow0 + 128 + r) * 2 + 1];
    float M = fmaxf(m0, m1);
    float w0 = exp2f(m0 - M) * l0, w1 = exp2f(m1 - M) * l1;
    float inv = 1.f / (w0 + w1);
    w0 *= inv; w1 *= inv;
    bf16x8 a = *reinterpret_cast<const bf16x8*>(pO + (prow0 + r) * 64 + d8 * 8);
    bf16x8 c = *reinterpret_cast<const bf16x8*>(pO + (prow0 + 128 + r) * 64 + d8 * 8);
    short res[8];
    #pragma unroll
    for (int i = 0; i < 8; ++i) res[i] = f2bf(w0 * bf2f(a[i]) + w1 * bf2f(c[i]));
    int t = (jj + 8) * 128 + r;
    *reinterpret_cast<bf16x8*>(ab + ((size_t)(b * T_ + t)) * D_ + h * HD_ + d8 * 8) =
        *reinterpret_cast<const bf16x8*>(res);
}

extern "C" void kernel_launch(void* const* d_in, const int* in_sizes, int n_in,
                              void* d_out, int out_size, void* d_ws, size_t ws_size,
                              hipStream_t stream) {
    const float* x  = (const float*)d_in[0];
    // d_in[1] = causal mask — structure known (triu k=1), ignored
    const float* Wq = (const float*)d_in[2];
    const float* bq = (const float*)d_in[3];
    const float* Wk = (const float*)d_in[4];
    const float* bk = (const float*)d_in[5];
    const float* Wv = (const float*)d_in[6];
    const float* bv = (const float*)d_in[7];
    const float* Wo = (const float*)d_in[8];
    const float* bo = (const float*)d_in[9];
    float* out = (float*)d_out;

    const size_t NX = (size_t)B_ * T_ * D_;   // 8388608
    const size_t NW = (size_t)D_ * D_;        // 1048576

    // ws layout (shorts). ab aliases xb: x dead after GEMM1; stream serializes.
    short* ws   = (short*)d_ws;
    short* xb   = ws;                //  x  bf16             (16 MB)
    short* ab   = ws;                //  attn out, aliases xb
    short* wqkv = xb + NX;           //  [Wq;Wk;Wv] bf16     ( 6 MB)
    short* wob  = wqkv + 3 * NW;     //  Wo bf16             ( 2 MB)
    short* qb   = wob + NW;          //  q (b,h,t,d) bf16    (16 MB)
    short* kb   = qb + NX;           //                      (16 MB)
    short* vb   = kb + NX;           //                      (16 MB)
    // split-K partials live in d_out (33.5 MB) used as scratch: pO 16.78 MB +
    // pml 2.1 MB; gemm2 fully overwrites d_out afterwards.
    short* pO   = (short*)d_out;
    float* pml  = (float*)((short*)d_out + (size_t)64 * 8 * 2 * 128 * 64);

    cast_kernel<<<(int)(NX / 1024), 256, 0, stream>>>(x, xb, (int)NX);
    cast_w_kernel<<<4096, 256, 0, stream>>>(Wq, Wk, Wv, Wo, wqkv, wob);

    gemm_kernel<0><<<dim3(24, 64), 256, 0, stream>>>(xb, wqkv, bq, bk, bv, qb, kb, vb, nullptr);
    attn_kernel<<<dim3(24, H_, B_), 256, 0, stream>>>(qb, kb, vb, ab, pO, pml);
    merge_kernel<<<2048, 256, 0, stream>>>(pO, pml, ab);
    gemm_kernel<1><<<dim3(8, 64), 256, 0, stream>>>(ab, wob, bo, nullptr, nullptr, nullptr,
                                                    nullptr, nullptr, out);
}